// Round 8
// baseline (426.099 us; speedup 1.0000x reference)
//
#include <hip/hip_runtime.h>

// Problem: z [32,256,32,32] fp32, codebook [1024,256] fp32
constexpr int D_ = 256;
constexpr int K_ = 1024;
constexpr int P_ = 1024;
constexpr int N_ = 32768;

// d_out layout (float32): z_q [8388608] ++ idx-as-float [32768] ++ loss [1]
constexpr int IDX_OFF  = 8388608;
constexpr int LOSS_OFF = 8421376;

// scratch parked in d_out's z_q region (gather overwrites it LAST):
constexpr int CB16_OFF = 0;        // fp16-split swizzled cb: 262144 floats
constexpr int CN_OFF   = 262400;   // cnorm [1024]  (gap absorbs B prefetch overrun)
constexpr int ZN_OFF   = 263424;   // zn [32768]
constexpr int CNT_OFF  = 296448;   // worklist counter (int)
constexpr int WL_OFF   = 296449;   // worklist [<=32768] (int row ids)

constexpr float RESCUE_MARGIN = 1e-4f;  // ~3.3 ulp(256)

typedef _Float16 half8 __attribute__((ext_vector_type(8)));
typedef float f32x4 __attribute__((ext_vector_type(4)));

// ---------------------------------------------------------------------------
// prep: blk<512: zn[row]=||z||^2 (PROVEN bit order); 512..1535: cnorm fp64
// (proven); 1536..1599: cb fp16-split swizzle. blk0 zeroes loss + counter.
__global__ __launch_bounds__(64) void vq_prep(const float* __restrict__ z,
                                              const float* __restrict__ cb,
                                              float* __restrict__ scratch,
                                              float* __restrict__ loss) {
  const int blk = blockIdx.x;
  const int lane = threadIdx.x;
  if (blk < 512) {
    const int n0 = blk * 64;
    const int b = n0 >> 10, p0 = n0 & (P_ - 1);
    const float* zp = z + (size_t)b * (D_ * P_) + p0 + lane;
    float a8[8];
    #pragma unroll
    for (int i = 0; i < 8; ++i) a8[i] = 0.0f;
    for (int oct = 0; oct < 32; ++oct) {
      #pragma unroll
      for (int i = 0; i < 8; ++i) {
        float v = zp[(size_t)(oct * 8 + i) * P_];
        a8[i] = fmaf(v, v, a8[i]);
      }
    }
    scratch[ZN_OFF + n0 + lane] = ((a8[0] + a8[1]) + (a8[2] + a8[3])) +
                                  ((a8[4] + a8[5]) + (a8[6] + a8[7]));
    if (blk == 0 && lane == 0) {
      *loss = 0.0f;
      ((int*)(scratch + CNT_OFF))[0] = 0;
    }
  } else if (blk < 1536) {
    const int k = blk - 512;
    const float* row = cb + (size_t)k * D_;
    double s = 0.0;
    #pragma unroll
    for (int i = 0; i < 4; ++i) {
      double v = (double)row[lane + i * 64];
      s = fma(v, v, s);
    }
    #pragma unroll
    for (int off = 32; off; off >>= 1) s += __shfl_down(s, off, 64);
    if (lane == 0) scratch[CN_OFF + k] = (float)s;
  } else {
    const int kt = blk - 1536;
    const int k = kt * 16 + (lane & 15);
    const int quad = lane >> 4;
    _Float16* cw = (_Float16*)(scratch + CB16_OFF);
    for (int ds = 0; ds < 8; ++ds) {
      const float* src = cb + (size_t)k * D_ + ds * 32 + quad * 8;
      half8 h, lo;
      #pragma unroll
      for (int j = 0; j < 8; ++j) {
        const float v = src[j] * 1024.0f;   // scale keeps lo out of subnormals
        const _Float16 hh = (_Float16)v;
        h[j] = hh;
        lo[j] = (_Float16)(v - (float)hh);
      }
      const int s = kt * 8 + ds;
      *(half8*)(cw + ((size_t)(s * 2 + 0) * 64 + lane) * 8) = h;
      *(half8*)(cw + ((size_t)(s * 2 + 1) * 64 + lane) * 8) = lo;
    }
  }
}

// ---------------------------------------------------------------------------
// main: fp16-split MFMA distance + argmin + worklist flagging.
// Block 256 thr = 4 waves, 64 rows. Wave w: rows (w&1)*32..+31, K-half (w>>1).
// Margin merge rewritten as plain sequential LDS merge (auditable).
__global__ __launch_bounds__(256, 2) void vq_mfma(const float* __restrict__ z,
                                                  float* __restrict__ scratch,
                                                  float* __restrict__ idxf) {
  const int t = threadIdx.x;
  const int w = t >> 6;
  const int l = t & 63;
  const int quad = l >> 4;
  const int col = l & 15;
  const int half = w >> 1;
  const int rpair = w & 1;
  const int n0 = blockIdx.x * 64;
  const int b = n0 >> 10;
  const int p0 = n0 & (P_ - 1);

  const _Float16* cbsw = (const _Float16*)(scratch + CB16_OFF);
  const float* cnorm = scratch + CN_OFF;
  const float* zn = scratch + ZN_OFF;

  __shared__ float Azs[64 * 33];
  __shared__ float sV1[2][64][16];
  __shared__ float sV2[2][64][16];
  __shared__ int   sI1[2][64][16];

  // ---- stage A fragments (z fp16-split, full depth, registers)
  half8 Ah[2][8], Al[2][8];
  const int pp = t & 63;
  const int dl0 = (t >> 6) * 8;
  for (int ds = 0; ds < 8; ++ds) {
    __syncthreads();
    #pragma unroll
    for (int i = 0; i < 8; ++i) {
      const int dloc = dl0 + i;
      Azs[pp * 33 + dloc] =
          z[(size_t)b * (D_ * P_) + (size_t)(ds * 32 + dloc) * P_ + p0 + pp];
    }
    __syncthreads();
    #pragma unroll
    for (int rt = 0; rt < 2; ++rt) {
      const int row_local = (rpair * 2 + rt) * 16 + col;
      const float* src = &Azs[row_local * 33 + quad * 8];
      half8 h, lo;
      #pragma unroll
      for (int j = 0; j < 8; ++j) {
        const float v = src[j];
        const _Float16 hh = (_Float16)v;
        h[j] = hh;
        lo[j] = (_Float16)(v - (float)hh);
      }
      Ah[rt][ds] = h;
      Al[rt][ds] = lo;
    }
  }

  float znr[2][4];
  #pragma unroll
  for (int rt = 0; rt < 2; ++rt)
    #pragma unroll
    for (int r = 0; r < 4; ++r)
      znr[rt][r] = zn[n0 + (rpair * 2 + rt) * 16 + quad * 4 + r];

  float m1[2][4], m2v[2][4];
  int i1[2][4];
  #pragma unroll
  for (int rt = 0; rt < 2; ++rt)
    #pragma unroll
    for (int r = 0; r < 4; ++r) { m1[rt][r] = 1e30f; m2v[rt][r] = 1e30f; i1[rt][r] = 0; }

  const int kt0 = half * 32;
  half8 Bh[4], Bl[4];
  #pragma unroll
  for (int s = 0; s < 2; ++s) {
    const int sg = kt0 * 8 + s;
    Bh[s] = *(const half8*)(cbsw + ((size_t)(sg * 2 + 0) * 64 + l) * 8);
    Bl[s] = *(const half8*)(cbsw + ((size_t)(sg * 2 + 1) * 64 + l) * 8);
  }

  for (int kt = kt0; kt < kt0 + 32; ++kt) {
    f32x4 a0 = {0.f, 0.f, 0.f, 0.f};
    f32x4 a1 = {0.f, 0.f, 0.f, 0.f};
    const float cnf = cnorm[kt * 16 + col];
    #pragma unroll
    for (int ds = 0; ds < 8; ++ds) {
      const int s = kt * 8 + ds;
      const int cur = ds & 3;
      const int nx = (ds + 2) & 3;
      Bh[nx] = *(const half8*)(cbsw + ((size_t)((s + 2) * 2 + 0) * 64 + l) * 8);
      Bl[nx] = *(const half8*)(cbsw + ((size_t)((s + 2) * 2 + 1) * 64 + l) * 8);
      a0 = __builtin_amdgcn_mfma_f32_16x16x32_f16(Ah[0][ds], Bh[cur], a0, 0, 0, 0);
      a1 = __builtin_amdgcn_mfma_f32_16x16x32_f16(Ah[1][ds], Bh[cur], a1, 0, 0, 0);
      a0 = __builtin_amdgcn_mfma_f32_16x16x32_f16(Ah[0][ds], Bl[cur], a0, 0, 0, 0);
      a1 = __builtin_amdgcn_mfma_f32_16x16x32_f16(Ah[1][ds], Bl[cur], a1, 0, 0, 0);
      a0 = __builtin_amdgcn_mfma_f32_16x16x32_f16(Al[0][ds], Bh[cur], a0, 0, 0, 0);
      a1 = __builtin_amdgcn_mfma_f32_16x16x32_f16(Al[1][ds], Bh[cur], a1, 0, 0, 0);
    }
    const int kg = kt * 16 + col;
    #pragma unroll
    for (int r = 0; r < 4; ++r) {
      const float s0 = fmaf(a0[r], -0x1p-9f, znr[0][r] + cnf);
      if (s0 < m1[0][r]) { m2v[0][r] = m1[0][r]; m1[0][r] = s0; i1[0][r] = kg; }
      else if (s0 < m2v[0][r]) m2v[0][r] = s0;
      const float s1 = fmaf(a1[r], -0x1p-9f, znr[1][r] + cnf);
      if (s1 < m1[1][r]) { m2v[1][r] = m1[1][r]; m1[1][r] = s1; i1[1][r] = kg; }
      else if (s1 < m2v[1][r]) m2v[1][r] = s1;
    }
  }

  // dump all per-lane triples to LDS; one thread per row merges sequentially
  #pragma unroll
  for (int rt = 0; rt < 2; ++rt)
    #pragma unroll
    for (int r = 0; r < 4; ++r) {
      const int row_local = (rpair * 2 + rt) * 16 + quad * 4 + r;
      sV1[half][row_local][col] = m1[rt][r];
      sV2[half][row_local][col] = m2v[rt][r];
      sI1[half][row_local][col] = i1[rt][r];
    }
  __syncthreads();

  if (t < 64) {
    float V1 = 1e30f, V2 = 1e30f;
    int I1 = 0x7fffffff;
    for (int h = 0; h < 2; ++h)
      for (int c = 0; c < 16; ++c) {
        const float v1 = sV1[h][t][c], v2 = sV2[h][t][c];
        const int iv = sI1[h][t][c];
        if (v1 < V1)       { V2 = fminf(V1, v2); V1 = v1; I1 = iv; }
        else if (v1 == V1) { I1 = min(I1, iv); V2 = V1; }   // distinct-k tie -> margin 0
        else               { V2 = fminf(V2, v1); }
      }
    idxf[n0 + t] = (float)I1;
    if (V2 - V1 < RESCUE_MARGIN) {
      int* cnt = (int*)(scratch + CNT_OFF);
      int* wl = (int*)(scratch + WL_OFF);
      const int pos = atomicAdd(cnt, 1);
      wl[pos] = n0 + t;
    }
  }
}

// ---------------------------------------------------------------------------
// rescue: exact fp32 rescore of worklisted rows (PROVEN scorer: ascending
// sequential fma over d; s = (zn+cn) - 2*dot; global first-index tie-break).
// Grid 4096 (1 row/block typical). Per thread: one k per pass (4 passes);
// each pass = 4 groups of 16 INDEPENDENT float4 loads then 64 fmas -> load
// chain depth 16 instead of 64 (R6/R7 lesson: serial chains = 23-45 us/row).
__global__ __launch_bounds__(256, 4) void vq_rescue(const float* __restrict__ z,
                                                    const float* __restrict__ cb,
                                                    const float* __restrict__ scratch,
                                                    float* __restrict__ idxf) {
  const int tid = threadIdx.x;
  const float* cnorm = scratch + CN_OFF;
  const float* zn = scratch + ZN_OFF;
  const int count = ((const int*)(scratch + CNT_OFF))[0];
  const int* wl = (const int*)(scratch + WL_OFF);

  __shared__ alignas(16) float zd[D_];
  __shared__ float rv[256];
  __shared__ int ri[256];

  for (int wi = blockIdx.x; wi < count; wi += gridDim.x) {
    const int n = wl[wi];
    const int b = n >> 10, p = n & (P_ - 1);
    zd[tid] = z[(size_t)b * (D_ * P_) + (size_t)tid * P_ + p];
    __syncthreads();
    const float zA = zn[n];
    const float4* zd4 = (const float4*)zd;

    float bv = 1e30f;
    int bi = 0x7fffffff;
    for (int pass = 0; pass < 4; ++pass) {
      const int k = pass * 256 + tid;            // ascending per thread
      const float4* cr = (const float4*)(cb + (size_t)k * D_);
      float acc = 0.0f;
      #pragma unroll
      for (int g = 0; g < 4; ++g) {
        float4 v[16];
        #pragma unroll
        for (int i = 0; i < 16; ++i) v[i] = cr[g * 16 + i];   // 16 loads in flight
        #pragma unroll
        for (int i = 0; i < 16; ++i) {
          const float4 zv = zd4[g * 16 + i];     // LDS broadcast
          acc = fmaf(zv.x, v[i].x, acc);         // d ascending -> bit-identical
          acc = fmaf(zv.y, v[i].y, acc);
          acc = fmaf(zv.z, v[i].z, acc);
          acc = fmaf(zv.w, v[i].w, acc);
        }
      }
      const float A = zA + cnorm[k];
      const float s = A - 2.0f * acc;
      if (s < bv) { bv = s; bi = k; }            // strict < keeps lowest k
    }
    rv[tid] = bv; ri[tid] = bi;
    __syncthreads();
    for (int off = 128; off >= 1; off >>= 1) {
      if (tid < off) {
        const float ov = rv[tid + off];
        const int oi = ri[tid + off];
        if (ov < rv[tid] || (ov == rv[tid] && oi < ri[tid])) { rv[tid] = ov; ri[tid] = oi; }
      }
      __syncthreads();
    }
    if (tid == 0) idxf[n] = (float)ri[0];
    __syncthreads();
  }
}

// ---------------------------------------------------------------------------
// gather: z_q = codebook[idx] into NCHW + loss; STE write out = z + (v - z).
__global__ __launch_bounds__(256) void vq_gather(const float* __restrict__ z,
                                                 const float* __restrict__ cb,
                                                 const float* __restrict__ idxf,
                                                 float* __restrict__ out,
                                                 float* __restrict__ loss) {
  const int tid = threadIdx.x;
  const int lane = tid & 63;
  const int w = tid >> 6;
  const int n0 = blockIdx.x * 64;
  const int b = n0 >> 10;
  const int p0 = n0 & (P_ - 1);
  const int p = p0 + lane;

  const int idx = (int)(idxf[n0 + lane] + 0.5f);
  const float4* crow4 = (const float4*)(cb + (size_t)idx * D_);
  const size_t base = (size_t)b * (D_ * P_) + p;

  float acc = 0.0f;
  #pragma unroll 4
  for (int ci = 0; ci < 16; ++ci) {
    const float4 v = crow4[w * 16 + ci];
    const int c = w * 64 + ci * 4;
    const float vv[4] = {v.x, v.y, v.z, v.w};
    #pragma unroll
    for (int u = 0; u < 4; ++u) {
      const size_t a = base + (size_t)(c + u) * P_;
      const float zv = z[a];
      const float d = vv[u] - zv;
      out[a] = zv + d;                  // fl32 STE, bit-exact
      acc = fmaf(d, d, acc);
    }
  }
  #pragma unroll
  for (int off = 32; off; off >>= 1) acc += __shfl_down(acc, off, 64);
  __shared__ float wsum[4];
  if (lane == 0) wsum[w] = acc;
  __syncthreads();
  if (tid == 0) {
    float s = wsum[0] + wsum[1] + wsum[2] + wsum[3];
    atomicAdd(loss, s * (1.25f / 8388608.0f));
  }
}

// ---------------------------------------------------------------------------
extern "C" void kernel_launch(void* const* d_in, const int* in_sizes, int n_in,
                              void* d_out, int out_size, void* d_ws, size_t ws_size,
                              hipStream_t stream) {
  const float* z = (const float*)d_in[0];
  const float* cb = (const float*)d_in[1];
  float* out = (float*)d_out;

  vq_prep<<<1600, 64, 0, stream>>>(z, cb, out, out + LOSS_OFF);
  vq_mfma<<<N_ / 64, 256, 0, stream>>>(z, out, out + IDX_OFF);
  vq_rescue<<<4096, 256, 0, stream>>>(z, cb, out, out + IDX_OFF);
  vq_gather<<<N_ / 64, 256, 0, stream>>>(z, cb, out + IDX_OFF, out, out + LOSS_OFF);
}

// Round 9
// 252.405 us; speedup vs baseline: 1.6882x; 1.6882x over previous
//
#include <hip/hip_runtime.h>

// Problem: z [32,256,32,32] fp32, codebook [1024,256] fp32
constexpr int D_ = 256;
constexpr int K_ = 1024;
constexpr int P_ = 1024;
constexpr int N_ = 32768;

// d_out layout (float32): z_q [8388608] ++ idx-as-float [32768] ++ loss [1]
constexpr int IDX_OFF  = 8388608;
constexpr int LOSS_OFF = 8421376;

// scratch parked in d_out's z_q region (gather overwrites it LAST):
constexpr int CB16_OFF = 0;        // fp16-split swizzled cb: 262144 floats
constexpr int CN_OFF   = 262400;   // cnorm [1024]  (gap absorbs B prefetch overrun)
constexpr int ZN_OFF   = 263424;   // zn [32768]
constexpr int CNT_OFF  = 296448;   // worklist counter (int)
constexpr int WL_OFF   = 296449;   // worklist [<=32768] (int row ids)

constexpr float RESCUE_MARGIN = 1e-4f;  // ~3.3 ulp(256)

typedef _Float16 half8 __attribute__((ext_vector_type(8)));
typedef float f32x4 __attribute__((ext_vector_type(4)));

// ---------------------------------------------------------------------------
// prep: blk<512: zn[row]=||z||^2 (PROVEN bit order); 512..1535: cnorm fp64
// (proven); 1536..1599: cb fp16-split swizzle. blk0 zeroes loss + counter.
__global__ __launch_bounds__(64) void vq_prep(const float* __restrict__ z,
                                              const float* __restrict__ cb,
                                              float* __restrict__ scratch,
                                              float* __restrict__ loss) {
  const int blk = blockIdx.x;
  const int lane = threadIdx.x;
  if (blk < 512) {
    const int n0 = blk * 64;
    const int b = n0 >> 10, p0 = n0 & (P_ - 1);
    const float* zp = z + (size_t)b * (D_ * P_) + p0 + lane;
    float a8[8];
    #pragma unroll
    for (int i = 0; i < 8; ++i) a8[i] = 0.0f;
    for (int oct = 0; oct < 32; ++oct) {
      #pragma unroll
      for (int i = 0; i < 8; ++i) {
        float v = zp[(size_t)(oct * 8 + i) * P_];
        a8[i] = fmaf(v, v, a8[i]);
      }
    }
    scratch[ZN_OFF + n0 + lane] = ((a8[0] + a8[1]) + (a8[2] + a8[3])) +
                                  ((a8[4] + a8[5]) + (a8[6] + a8[7]));
    if (blk == 0 && lane == 0) {
      *loss = 0.0f;
      ((int*)(scratch + CNT_OFF))[0] = 0;
    }
  } else if (blk < 1536) {
    const int k = blk - 512;
    const float* row = cb + (size_t)k * D_;
    double s = 0.0;
    #pragma unroll
    for (int i = 0; i < 4; ++i) {
      double v = (double)row[lane + i * 64];
      s = fma(v, v, s);
    }
    #pragma unroll
    for (int off = 32; off; off >>= 1) s += __shfl_down(s, off, 64);
    if (lane == 0) scratch[CN_OFF + k] = (float)s;
  } else {
    const int kt = blk - 1536;
    const int k = kt * 16 + (lane & 15);
    const int quad = lane >> 4;
    _Float16* cw = (_Float16*)(scratch + CB16_OFF);
    for (int ds = 0; ds < 8; ++ds) {
      const float* src = cb + (size_t)k * D_ + ds * 32 + quad * 8;
      half8 h, lo;
      #pragma unroll
      for (int j = 0; j < 8; ++j) {
        const float v = src[j] * 1024.0f;   // scale keeps lo out of subnormals
        const _Float16 hh = (_Float16)v;
        h[j] = hh;
        lo[j] = (_Float16)(v - (float)hh);
      }
      const int s = kt * 8 + ds;
      *(half8*)(cw + ((size_t)(s * 2 + 0) * 64 + lane) * 8) = h;
      *(half8*)(cw + ((size_t)(s * 2 + 1) * 64 + lane) * 8) = lo;
    }
  }
}

// ---------------------------------------------------------------------------
// main: fp16-split MFMA distance + argmin + worklist flagging (unchanged,
// passing with absmax 0.0).
__global__ __launch_bounds__(256, 2) void vq_mfma(const float* __restrict__ z,
                                                  float* __restrict__ scratch,
                                                  float* __restrict__ idxf) {
  const int t = threadIdx.x;
  const int w = t >> 6;
  const int l = t & 63;
  const int quad = l >> 4;
  const int col = l & 15;
  const int half = w >> 1;
  const int rpair = w & 1;
  const int n0 = blockIdx.x * 64;
  const int b = n0 >> 10;
  const int p0 = n0 & (P_ - 1);

  const _Float16* cbsw = (const _Float16*)(scratch + CB16_OFF);
  const float* cnorm = scratch + CN_OFF;
  const float* zn = scratch + ZN_OFF;

  __shared__ float Azs[64 * 33];
  __shared__ float sV1[2][64][16];
  __shared__ float sV2[2][64][16];
  __shared__ int   sI1[2][64][16];

  half8 Ah[2][8], Al[2][8];
  const int pp = t & 63;
  const int dl0 = (t >> 6) * 8;
  for (int ds = 0; ds < 8; ++ds) {
    __syncthreads();
    #pragma unroll
    for (int i = 0; i < 8; ++i) {
      const int dloc = dl0 + i;
      Azs[pp * 33 + dloc] =
          z[(size_t)b * (D_ * P_) + (size_t)(ds * 32 + dloc) * P_ + p0 + pp];
    }
    __syncthreads();
    #pragma unroll
    for (int rt = 0; rt < 2; ++rt) {
      const int row_local = (rpair * 2 + rt) * 16 + col;
      const float* src = &Azs[row_local * 33 + quad * 8];
      half8 h, lo;
      #pragma unroll
      for (int j = 0; j < 8; ++j) {
        const float v = src[j];
        const _Float16 hh = (_Float16)v;
        h[j] = hh;
        lo[j] = (_Float16)(v - (float)hh);
      }
      Ah[rt][ds] = h;
      Al[rt][ds] = lo;
    }
  }

  float znr[2][4];
  #pragma unroll
  for (int rt = 0; rt < 2; ++rt)
    #pragma unroll
    for (int r = 0; r < 4; ++r)
      znr[rt][r] = zn[n0 + (rpair * 2 + rt) * 16 + quad * 4 + r];

  float m1[2][4], m2v[2][4];
  int i1[2][4];
  #pragma unroll
  for (int rt = 0; rt < 2; ++rt)
    #pragma unroll
    for (int r = 0; r < 4; ++r) { m1[rt][r] = 1e30f; m2v[rt][r] = 1e30f; i1[rt][r] = 0; }

  const int kt0 = half * 32;
  half8 Bh[4], Bl[4];
  #pragma unroll
  for (int s = 0; s < 2; ++s) {
    const int sg = kt0 * 8 + s;
    Bh[s] = *(const half8*)(cbsw + ((size_t)(sg * 2 + 0) * 64 + l) * 8);
    Bl[s] = *(const half8*)(cbsw + ((size_t)(sg * 2 + 1) * 64 + l) * 8);
  }

  for (int kt = kt0; kt < kt0 + 32; ++kt) {
    f32x4 a0 = {0.f, 0.f, 0.f, 0.f};
    f32x4 a1 = {0.f, 0.f, 0.f, 0.f};
    const float cnf = cnorm[kt * 16 + col];
    #pragma unroll
    for (int ds = 0; ds < 8; ++ds) {
      const int s = kt * 8 + ds;
      const int cur = ds & 3;
      const int nx = (ds + 2) & 3;
      Bh[nx] = *(const half8*)(cbsw + ((size_t)((s + 2) * 2 + 0) * 64 + l) * 8);
      Bl[nx] = *(const half8*)(cbsw + ((size_t)((s + 2) * 2 + 1) * 64 + l) * 8);
      a0 = __builtin_amdgcn_mfma_f32_16x16x32_f16(Ah[0][ds], Bh[cur], a0, 0, 0, 0);
      a1 = __builtin_amdgcn_mfma_f32_16x16x32_f16(Ah[1][ds], Bh[cur], a1, 0, 0, 0);
      a0 = __builtin_amdgcn_mfma_f32_16x16x32_f16(Ah[0][ds], Bl[cur], a0, 0, 0, 0);
      a1 = __builtin_amdgcn_mfma_f32_16x16x32_f16(Ah[1][ds], Bl[cur], a1, 0, 0, 0);
      a0 = __builtin_amdgcn_mfma_f32_16x16x32_f16(Al[0][ds], Bh[cur], a0, 0, 0, 0);
      a1 = __builtin_amdgcn_mfma_f32_16x16x32_f16(Al[1][ds], Bh[cur], a1, 0, 0, 0);
    }
    const int kg = kt * 16 + col;
    #pragma unroll
    for (int r = 0; r < 4; ++r) {
      const float s0 = fmaf(a0[r], -0x1p-9f, znr[0][r] + cnf);
      if (s0 < m1[0][r]) { m2v[0][r] = m1[0][r]; m1[0][r] = s0; i1[0][r] = kg; }
      else if (s0 < m2v[0][r]) m2v[0][r] = s0;
      const float s1 = fmaf(a1[r], -0x1p-9f, znr[1][r] + cnf);
      if (s1 < m1[1][r]) { m2v[1][r] = m1[1][r]; m1[1][r] = s1; i1[1][r] = kg; }
      else if (s1 < m2v[1][r]) m2v[1][r] = s1;
    }
  }

  #pragma unroll
  for (int rt = 0; rt < 2; ++rt)
    #pragma unroll
    for (int r = 0; r < 4; ++r) {
      const int row_local = (rpair * 2 + rt) * 16 + quad * 4 + r;
      sV1[half][row_local][col] = m1[rt][r];
      sV2[half][row_local][col] = m2v[rt][r];
      sI1[half][row_local][col] = i1[rt][r];
    }
  __syncthreads();

  if (t < 64) {
    float V1 = 1e30f, V2 = 1e30f;
    int I1 = 0x7fffffff;
    for (int h = 0; h < 2; ++h)
      for (int c = 0; c < 16; ++c) {
        const float v1 = sV1[h][t][c], v2 = sV2[h][t][c];
        const int iv = sI1[h][t][c];
        if (v1 < V1)       { V2 = fminf(V1, v2); V1 = v1; I1 = iv; }
        else if (v1 == V1) { I1 = min(I1, iv); V2 = V1; }
        else               { V2 = fminf(V2, v1); }
      }
    idxf[n0 + t] = (float)I1;
    if (V2 - V1 < RESCUE_MARGIN) {
      int* cnt = (int*)(scratch + CNT_OFF);
      int* wl = (int*)(scratch + WL_OFF);
      const int pos = atomicAdd(cnt, 1);
      wl[pos] = n0 + t;
    }
  }
}

// ---------------------------------------------------------------------------
// rescue (BATCHED): 8 rows per codebook sweep. Stage 8 z-rows in LDS; thread
// owns k = 4*tid..4*tid+3 (one pass covers K=1024) with 8x4 = 32 independent
// fma chains -> per d4-step: 4 global float4 + 8 LDS broadcasts feed 128
// fmas (latency hidden by arithmetic, nothing for the compiler to fight).
// R8 lesson: per-row codebook sweeps = count x 1 MB traffic = 235 us.
// Bit-exactness: per (row,k) chain is ascending-d sequential; k ascending
// per thread (strict <); (value,index)-lexicographic block reduction.
__global__ __launch_bounds__(256, 4) void vq_rescue(const float* __restrict__ z,
                                                    const float* __restrict__ cb,
                                                    const float* __restrict__ scratch,
                                                    float* __restrict__ idxf) {
  const int tid = threadIdx.x;
  const float* cnorm = scratch + CN_OFF;
  const float* zn = scratch + ZN_OFF;
  const int count = ((const int*)(scratch + CNT_OFF))[0];
  const int* wl = (const int*)(scratch + WL_OFF);

  __shared__ alignas(16) float zb[8][D_];
  __shared__ int nrow[8];
  __shared__ float rv[256];
  __shared__ int ri[256];

  for (int base = blockIdx.x * 8; base < count; base += gridDim.x * 8) {
    const int take = min(8, count - base);
    if (tid < 8) nrow[tid] = wl[base + (tid < take ? tid : 0)];
    __syncthreads();
    #pragma unroll
    for (int r = 0; r < 8; ++r) {
      const int n = nrow[r];
      const int b = n >> 10, p = n & (P_ - 1);
      zb[r][tid] = z[(size_t)b * (D_ * P_) + (size_t)tid * P_ + p];
    }
    __syncthreads();

    const int k0 = tid * 4;
    const float4* __restrict__ cr0 = (const float4*)(cb + (size_t)(k0 + 0) * D_);
    const float4* __restrict__ cr1 = (const float4*)(cb + (size_t)(k0 + 1) * D_);
    const float4* __restrict__ cr2 = (const float4*)(cb + (size_t)(k0 + 2) * D_);
    const float4* __restrict__ cr3 = (const float4*)(cb + (size_t)(k0 + 3) * D_);

    float acc[8][4];
    #pragma unroll
    for (int r = 0; r < 8; ++r)
      #pragma unroll
      for (int j = 0; j < 4; ++j) acc[r][j] = 0.0f;

    for (int d4 = 0; d4 < 64; ++d4) {
      const float4 v0 = cr0[d4], v1 = cr1[d4], v2 = cr2[d4], v3 = cr3[d4];
      #pragma unroll
      for (int r = 0; r < 8; ++r) {
        const float4 zv = ((const float4*)zb[r])[d4];   // LDS broadcast
        acc[r][0] = fmaf(zv.x, v0.x, acc[r][0]);
        acc[r][0] = fmaf(zv.y, v0.y, acc[r][0]);
        acc[r][0] = fmaf(zv.z, v0.z, acc[r][0]);
        acc[r][0] = fmaf(zv.w, v0.w, acc[r][0]);
        acc[r][1] = fmaf(zv.x, v1.x, acc[r][1]);
        acc[r][1] = fmaf(zv.y, v1.y, acc[r][1]);
        acc[r][1] = fmaf(zv.z, v1.z, acc[r][1]);
        acc[r][1] = fmaf(zv.w, v1.w, acc[r][1]);
        acc[r][2] = fmaf(zv.x, v2.x, acc[r][2]);
        acc[r][2] = fmaf(zv.y, v2.y, acc[r][2]);
        acc[r][2] = fmaf(zv.z, v2.z, acc[r][2]);
        acc[r][2] = fmaf(zv.w, v2.w, acc[r][2]);
        acc[r][3] = fmaf(zv.x, v3.x, acc[r][3]);
        acc[r][3] = fmaf(zv.y, v3.y, acc[r][3]);
        acc[r][3] = fmaf(zv.z, v3.z, acc[r][3]);
        acc[r][3] = fmaf(zv.w, v3.w, acc[r][3]);
      }
    }

    for (int r = 0; r < 8; ++r) {
      const int n = nrow[r];
      const float zA = zn[n];
      float bv = 1e30f;
      int bi = 0x7fffffff;
      #pragma unroll
      for (int j = 0; j < 4; ++j) {               // k ascending -> strict <
        const float A = zA + cnorm[k0 + j];
        const float s = A - 2.0f * acc[r][j];
        if (s < bv) { bv = s; bi = k0 + j; }
      }
      rv[tid] = bv; ri[tid] = bi;
      __syncthreads();
      for (int off = 128; off >= 1; off >>= 1) {
        if (tid < off) {
          const float ov = rv[tid + off];
          const int oi = ri[tid + off];
          if (ov < rv[tid] || (ov == rv[tid] && oi < ri[tid])) { rv[tid] = ov; ri[tid] = oi; }
        }
        __syncthreads();
      }
      if (tid == 0 && r < take) idxf[n] = (float)ri[0];
      __syncthreads();
    }
  }
}

// ---------------------------------------------------------------------------
// gather: z_q = codebook[idx] into NCHW + loss; STE write out = z + (v - z).
__global__ __launch_bounds__(256) void vq_gather(const float* __restrict__ z,
                                                 const float* __restrict__ cb,
                                                 const float* __restrict__ idxf,
                                                 float* __restrict__ out,
                                                 float* __restrict__ loss) {
  const int tid = threadIdx.x;
  const int lane = tid & 63;
  const int w = tid >> 6;
  const int n0 = blockIdx.x * 64;
  const int b = n0 >> 10;
  const int p0 = n0 & (P_ - 1);
  const int p = p0 + lane;

  const int idx = (int)(idxf[n0 + lane] + 0.5f);
  const float4* crow4 = (const float4*)(cb + (size_t)idx * D_);
  const size_t base = (size_t)b * (D_ * P_) + p;

  float acc = 0.0f;
  #pragma unroll 4
  for (int ci = 0; ci < 16; ++ci) {
    const float4 v = crow4[w * 16 + ci];
    const int c = w * 64 + ci * 4;
    const float vv[4] = {v.x, v.y, v.z, v.w};
    #pragma unroll
    for (int u = 0; u < 4; ++u) {
      const size_t a = base + (size_t)(c + u) * P_;
      const float zv = z[a];
      const float d = vv[u] - zv;
      out[a] = zv + d;                  // fl32 STE, bit-exact
      acc = fmaf(d, d, acc);
    }
  }
  #pragma unroll
  for (int off = 32; off; off >>= 1) acc += __shfl_down(acc, off, 64);
  __shared__ float wsum[4];
  if (lane == 0) wsum[w] = acc;
  __syncthreads();
  if (tid == 0) {
    float s = wsum[0] + wsum[1] + wsum[2] + wsum[3];
    atomicAdd(loss, s * (1.25f / 8388608.0f));
  }
}

// ---------------------------------------------------------------------------
extern "C" void kernel_launch(void* const* d_in, const int* in_sizes, int n_in,
                              void* d_out, int out_size, void* d_ws, size_t ws_size,
                              hipStream_t stream) {
  const float* z = (const float*)d_in[0];
  const float* cb = (const float*)d_in[1];
  float* out = (float*)d_out;

  vq_prep<<<1600, 64, 0, stream>>>(z, cb, out, out + LOSS_OFF);
  vq_mfma<<<N_ / 64, 256, 0, stream>>>(z, out, out + IDX_OFF);
  vq_rescue<<<128, 256, 0, stream>>>(z, cb, out, out + IDX_OFF);
  vq_gather<<<N_ / 64, 256, 0, stream>>>(z, cb, out + IDX_OFF, out, out + LOSS_OFF);
}